// Round 1
// baseline (130.447 us; speedup 1.0000x reference)
//
#include <hip/hip_runtime.h>

// StochasticPool2d: x (B=32, C=64, H=224, W=224) f32.
// mp = maxpool2x2 stride1 over x padded (right/bottom) with 0.
// out[b,c,i,j] = mp[b,c, h_off[i]+2i, w_off[j]+2j]   -> (32,64,112,112)
//
// Direct gather: out = max(x[h][w], x[h][w+1]|0, x[h+1][w]|0, x[h+1][w+1]|0)
// where |0 means "0 if out of range" (pad value participates in the max).

#define H 224
#define W 224
#define NH 112
#define NW 112

__global__ __launch_bounds__(256) void spool_kernel(
    const float* __restrict__ x,
    const int* __restrict__ h_off,
    const int* __restrict__ w_off,
    float* __restrict__ out,
    int total) {
  int idx = blockIdx.x * blockDim.x + threadIdx.x;
  if (idx >= total) return;

  int j = idx % NW;
  int t = idx / NW;
  int i = t % NH;
  int plane = t / NH;  // b*C + c

  int h = h_off[i] + 2 * i;   // in [0, 223]
  int w = w_off[j] + 2 * j;   // in [0, 223]

  const float* p = x + ((size_t)plane * H + h) * W;

  float v00 = p[w];
  float v01 = (w + 1 < W) ? p[w + 1] : 0.0f;
  float m = fmaxf(v00, v01);
  if (h + 1 < H) {
    const float* q = p + W;
    float v10 = q[w];
    float v11 = (w + 1 < W) ? q[w + 1] : 0.0f;
    m = fmaxf(m, fmaxf(v10, v11));
  } else {
    m = fmaxf(m, 0.0f);  // bottom pad row contributes 0
  }
  out[idx] = m;
}

extern "C" void kernel_launch(void* const* d_in, const int* in_sizes, int n_in,
                              void* d_out, int out_size, void* d_ws, size_t ws_size,
                              hipStream_t stream) {
  const float* x = (const float*)d_in[0];
  const int* h_off = (const int*)d_in[1];
  const int* w_off = (const int*)d_in[2];
  float* out = (float*)d_out;

  int total = out_size;  // 32*64*112*112
  int block = 256;
  int grid = (total + block - 1) / block;
  spool_kernel<<<grid, block, 0, stream>>>(x, h_off, w_off, out, total);
}